// Round 1
// baseline (607.101 us; speedup 1.0000x reference)
//
#include <hip/hip_runtime.h>
#include <math.h>

#define NN 50000
#define NE 800000
#define CH 32
#define GEPS 1e-15f
#define BN_EPS 1e-5f

// inv[k*3+d] = -0.5/(eps + sigma^2), packed: [0..14]=conv1, [15..29]=conv2, [30..32]=skip
__global__ void precompute_inv(const float* __restrict__ sig1, const float* __restrict__ sig2,
                               const float* __restrict__ sigs, float* __restrict__ inv) {
    int t = threadIdx.x;
    if (t < 15)      { float s = sig1[t];      inv[t] = -0.5f / (GEPS + s * s); }
    else if (t < 30) { float s = sig2[t - 15]; inv[t] = -0.5f / (GEPS + s * s); }
    else if (t < 33) { float s = sigs[t - 30]; inv[t] = -0.5f / (GEPS + s * s); }
}

// P[n][0:K*32] = x[n] @ g ; P[n][K*32:(K+1)*32] = x[n] @ root + bias
// blockDim must be (K+1)*32. Each thread keeps its W column in registers.
template <int K>
__global__ void proj_kernel(const float* __restrict__ xin, const float* __restrict__ g,
                            const float* __restrict__ root, const float* __restrict__ bias,
                            float* __restrict__ P) {
    constexpr int KC = K * 32;
    constexpr int COLS = (K + 1) * 32;
    const int t = threadIdx.x;

    float w[32];
    if (t < KC) {
#pragma unroll
        for (int i = 0; i < 32; i++) w[i] = g[i * KC + t];
    } else {
#pragma unroll
        for (int i = 0; i < 32; i++) w[i] = root[i * 32 + (t - KC)];
    }
    float b = (t >= KC) ? bias[t - KC] : 0.0f;

    constexpr int NPB = 4;  // nodes per iteration
    __shared__ float xs[NPB * 32];
    for (int n0 = blockIdx.x * NPB; n0 < NN; n0 += gridDim.x * NPB) {
        int nrows = NN - n0; if (nrows > NPB) nrows = NPB;
        for (int j = t; j < nrows * 32; j += COLS) xs[j] = xin[(size_t)n0 * 32 + j];
        __syncthreads();
        for (int r = 0; r < nrows; r++) {
            float acc = b;
#pragma unroll
            for (int i = 0; i < 32; i++) acc += w[i] * xs[r * 32 + i];
            P[(size_t)(n0 + r) * COLS + t] = acc;
        }
        __syncthreads();
    }
}

// 32 lanes per edge; lane = output channel. Gathers proj rows (coalesced), scatters via atomics.
template <int K, bool COUNT>
__global__ void edge_kernel(const int* __restrict__ ei, const float* __restrict__ ea,
                            const float* __restrict__ mu, const float* __restrict__ inv,
                            const float* __restrict__ P, float* __restrict__ agg,
                            float* __restrict__ cnt) {
    constexpr int STRIDE = (K + 1) * 32;
    long long idx = (long long)blockIdx.x * blockDim.x + threadIdx.x;
    int e = (int)(idx >> 5);
    int lane = (int)(idx & 31);
    if (e >= NE) return;

    int src = ei[e];
    int dst = ei[NE + e];
    float a0 = ea[e * 3 + 0], a1 = ea[e * 3 + 1], a2 = ea[e * 3 + 2];

    const float* Prow = P + (size_t)src * STRIDE + lane;
    float msg = 0.0f;
#pragma unroll
    for (int k = 0; k < K; k++) {
        float d0 = a0 - mu[k * 3 + 0];
        float d1 = a1 - mu[k * 3 + 1];
        float d2 = a2 - mu[k * 3 + 2];
        float ex = inv[k * 3 + 0] * d0 * d0 + inv[k * 3 + 1] * d1 * d1 + inv[k * 3 + 2] * d2 * d2;
        msg += __expf(ex) * Prow[k * 32];
    }
    atomicAdd(&agg[(size_t)dst * 32 + lane], msg);
    if (COUNT && lane == 0) atomicAdd(&cnt[dst], 1.0f);
}

// c = agg/max(cnt,1) + term (in place into agg); accumulate per-channel sum/sumsq into stats[64]
__global__ void node_stats_kernel(float* __restrict__ agg, const float* __restrict__ P,
                                  int pstride, int termoff, const float* __restrict__ cnt,
                                  float* __restrict__ stats) {
    float lsum = 0.0f, lsq = 0.0f;
    const int total = NN * 32;
    for (int idx = blockIdx.x * blockDim.x + threadIdx.x; idx < total;
         idx += gridDim.x * blockDim.x) {
        int n = idx >> 5, ch = idx & 31;
        float c = agg[idx] / fmaxf(cnt[n], 1.0f) + P[(size_t)n * pstride + termoff + ch];
        agg[idx] = c;
        lsum += c;
        lsq += c * c;
    }
    __shared__ float ssum[256], ssq[256];
    int t = threadIdx.x;
    ssum[t] = lsum; ssq[t] = lsq;
    __syncthreads();
    for (int off = 128; off >= 32; off >>= 1) {
        if (t < off) { ssum[t] += ssum[t + off]; ssq[t] += ssq[t + off]; }
        __syncthreads();
    }
    if (t < 32) {
        atomicAdd(&stats[t], ssum[t]);
        atomicAdd(&stats[32 + t], ssq[t]);
    }
}

// mode 0: out = elu(bn(c)); mode 1: out = bn(c); mode 2: out = elu(bn(c) + addend)
__global__ void apply_kernel(const float* __restrict__ c, const float* __restrict__ stats,
                             const float* __restrict__ gamma, const float* __restrict__ beta,
                             const float* __restrict__ addend, float* __restrict__ out, int mode) {
    int idx = blockIdx.x * blockDim.x + threadIdx.x;
    if (idx >= NN * 32) return;
    int ch = idx & 31;
    const float invN = 1.0f / (float)NN;
    float mean = stats[ch] * invN;
    float var = stats[32 + ch] * invN - mean * mean;
    float v = gamma[ch] * (c[idx] - mean) * rsqrtf(var + BN_EPS) + beta[ch];
    if (mode == 2) v += addend[idx];
    if (mode != 1) v = (v > 0.0f) ? v : (__expf(v) - 1.0f);
    out[idx] = v;
}

extern "C" void kernel_launch(void* const* d_in, const int* in_sizes, int n_in,
                              void* d_out, int out_size, void* d_ws, size_t ws_size,
                              hipStream_t stream) {
    const float* x     = (const float*)d_in[0];
    const float* ea    = (const float*)d_in[1];
    const float* g1    = (const float*)d_in[2];
    const float* mu1   = (const float*)d_in[3];
    const float* sig1  = (const float*)d_in[4];
    const float* root1 = (const float*)d_in[5];
    const float* b1    = (const float*)d_in[6];
    const float* gam1  = (const float*)d_in[7];
    const float* bet1  = (const float*)d_in[8];
    const float* g2    = (const float*)d_in[9];
    const float* mu2   = (const float*)d_in[10];
    const float* sig2  = (const float*)d_in[11];
    const float* root2 = (const float*)d_in[12];
    const float* b2    = (const float*)d_in[13];
    const float* gam2  = (const float*)d_in[14];
    const float* bet2  = (const float*)d_in[15];
    const float* gs    = (const float*)d_in[16];
    const float* mus   = (const float*)d_in[17];
    const float* sigs  = (const float*)d_in[18];
    const float* roots = (const float*)d_in[19];
    const float* bs    = (const float*)d_in[20];
    const float* gams  = (const float*)d_in[21];
    const float* bets  = (const float*)d_in[22];
    const int*   ei    = (const int*)d_in[23];
    float* out = (float*)d_out;

    // workspace layout (floats)
    float* A = (float*)d_ws;                       // proj+term buffer: NN*192
    float* B = A + (size_t)NN * 192;               // agg / c buffer:   NN*32
    float* C = B + (size_t)NN * 32;                // cnt:              NN
    float* D = C + NN;                             // h:                NN*32
    float* E = D + (size_t)NN * 32;                // s:                NN*32
    float* F = E + (size_t)NN * 32;                // stats: 3*64
    float* G = F + 192;                            // inv params: 33

    const int edgeBlocks = (NE * 32 + 255) / 256;
    const int applyBlocks = (NN * 32 + 255) / 256;

    hipMemsetAsync(C, 0, NN * sizeof(float), stream);
    hipMemsetAsync(F, 0, 192 * sizeof(float), stream);
    precompute_inv<<<1, 64, 0, stream>>>(sig1, sig2, sigs, G);

    // ---- conv1: h = elu(bn(gmm_conv(x, g1...)))
    proj_kernel<5><<<512, 192, 0, stream>>>(x, g1, root1, b1, A);
    hipMemsetAsync(B, 0, (size_t)NN * 32 * sizeof(float), stream);
    edge_kernel<5, true><<<edgeBlocks, 256, 0, stream>>>(ei, ea, mu1, G + 0, A, B, C);
    node_stats_kernel<<<1024, 256, 0, stream>>>(B, A, 192, 160, C, F + 0);
    apply_kernel<<<applyBlocks, 256, 0, stream>>>(B, F + 0, gam1, bet1, nullptr, D, 0);

    // ---- skip: s = bn(gmm_conv(x, gs...))   (K=1)
    proj_kernel<1><<<512, 64, 0, stream>>>(x, gs, roots, bs, A);
    hipMemsetAsync(B, 0, (size_t)NN * 32 * sizeof(float), stream);
    edge_kernel<1, false><<<edgeBlocks, 256, 0, stream>>>(ei, ea, mus, G + 30, A, B, nullptr);
    node_stats_kernel<<<1024, 256, 0, stream>>>(B, A, 64, 32, C, F + 64);
    apply_kernel<<<applyBlocks, 256, 0, stream>>>(B, F + 64, gams, bets, nullptr, E, 1);

    // ---- conv2 on h, then out = elu(bn(conv2) + s)
    proj_kernel<5><<<512, 192, 0, stream>>>(D, g2, root2, b2, A);
    hipMemsetAsync(B, 0, (size_t)NN * 32 * sizeof(float), stream);
    edge_kernel<5, false><<<edgeBlocks, 256, 0, stream>>>(ei, ea, mu2, G + 15, A, B, nullptr);
    node_stats_kernel<<<1024, 256, 0, stream>>>(B, A, 192, 160, C, F + 128);
    apply_kernel<<<applyBlocks, 256, 0, stream>>>(B, F + 128, gam2, bet2, E, out, 2);
}

// Round 2
// 578.672 us; speedup vs baseline: 1.0491x; 1.0491x over previous
//
#include <hip/hip_runtime.h>
#include <hip/hip_fp16.h>
#include <math.h>

#define NN 50000
#define NE 800000
#define GEPS 1e-15f
#define BN_EPS 1e-5f

// inv[k*3+d] = -0.5/(eps + sigma^2): [0..14]=conv1, [15..29]=conv2, [30..32]=skip
__global__ void precompute_inv(const float* __restrict__ sig1, const float* __restrict__ sig2,
                               const float* __restrict__ sigs, float* __restrict__ inv) {
    int t = threadIdx.x;
    if (t < 15)      { float s = sig1[t];      inv[t] = -0.5f / (GEPS + s * s); }
    else if (t < 30) { float s = sig2[t - 15]; inv[t] = -0.5f / (GEPS + s * s); }
    else if (t < 33) { float s = sigs[t - 30]; inv[t] = -0.5f / (GEPS + s * s); }
}

__global__ void hist_kernel(const int* __restrict__ ei, int* __restrict__ deg) {
    int e = blockIdx.x * blockDim.x + threadIdx.x;
    if (e < NE) atomicAdd(&deg[ei[NE + e]], 1);
}

// single-block exclusive scan of deg[NN] -> rowstart, cursor
__global__ void scan_kernel(const int* __restrict__ deg, int* __restrict__ rowstart,
                            int* __restrict__ cursor) {
    __shared__ int sh[1024];
    const int t = threadIdx.x;
    const int CHUNK = (NN + 1023) / 1024;  // 49
    int base = t * CHUNK;
    int s = 0;
    for (int i = 0; i < CHUNK; i++) { int j = base + i; if (j < NN) s += deg[j]; }
    sh[t] = s;
    __syncthreads();
    for (int off = 1; off < 1024; off <<= 1) {
        int v = (t >= off) ? sh[t - off] : 0;
        __syncthreads();
        sh[t] += v;
        __syncthreads();
    }
    int run = (t == 0) ? 0 : sh[t - 1];
    for (int i = 0; i < CHUNK; i++) {
        int j = base + i;
        if (j < NN) { rowstart[j] = run; cursor[j] = run; run += deg[j]; }
    }
}

// scatter edges into CSR order; precompute all 11 gaussian weights (fp16) in CSR order
__global__ void reorder_kernel(const int* __restrict__ ei, const float* __restrict__ ea,
                               const float* __restrict__ mu1, const float* __restrict__ mu2,
                               const float* __restrict__ mus, const float* __restrict__ inv,
                               int* __restrict__ cursor, int* __restrict__ srcs,
                               __half* __restrict__ wA, __half* __restrict__ wB,
                               __half* __restrict__ wS) {
    int e = blockIdx.x * blockDim.x + threadIdx.x;
    if (e >= NE) return;
    int src = ei[e];
    int dst = ei[NE + e];
    float a0 = ea[e * 3 + 0], a1 = ea[e * 3 + 1], a2 = ea[e * 3 + 2];
    int pos = atomicAdd(&cursor[dst], 1);
    srcs[pos] = src;
#pragma unroll
    for (int k = 0; k < 5; k++) {
        float d0 = a0 - mu1[k * 3 + 0], d1 = a1 - mu1[k * 3 + 1], d2 = a2 - mu1[k * 3 + 2];
        float ex = inv[k * 3] * d0 * d0 + inv[k * 3 + 1] * d1 * d1 + inv[k * 3 + 2] * d2 * d2;
        wA[(size_t)pos * 5 + k] = __float2half(__expf(ex));
    }
#pragma unroll
    for (int k = 0; k < 5; k++) {
        float d0 = a0 - mu2[k * 3 + 0], d1 = a1 - mu2[k * 3 + 1], d2 = a2 - mu2[k * 3 + 2];
        float ex = inv[15 + k * 3] * d0 * d0 + inv[15 + k * 3 + 1] * d1 * d1 + inv[15 + k * 3 + 2] * d2 * d2;
        wB[(size_t)pos * 5 + k] = __float2half(__expf(ex));
    }
    {
        float d0 = a0 - mus[0], d1 = a1 - mus[1], d2 = a2 - mus[2];
        float ex = inv[30] * d0 * d0 + inv[31] * d1 * d1 + inv[32] * d2 * d2;
        wS[pos] = __float2half(__expf(ex));
    }
}

// pass A projection: x -> PA[n][192] fp16 (0..159: g1-proj, 160..191: gs-proj),
//                    R1[n][32] fp32 (x@root1+b1), Rs[n][32] fp32 (x@roots+bs). block=256.
__global__ void projA_kernel(const float* __restrict__ x, const float* __restrict__ g1,
                             const float* __restrict__ gs, const float* __restrict__ root1,
                             const float* __restrict__ b1, const float* __restrict__ roots,
                             const float* __restrict__ bs, __half* __restrict__ PA,
                             float* __restrict__ R1, float* __restrict__ Rs) {
    const int t = threadIdx.x;
    float w[32];
    float b = 0.0f;
    if (t < 160) {
#pragma unroll
        for (int i = 0; i < 32; i++) w[i] = g1[i * 160 + t];
    } else if (t < 192) {
        int c = t - 160;
#pragma unroll
        for (int i = 0; i < 32; i++) w[i] = gs[i * 32 + c];
    } else if (t < 224) {
        int c = t - 192;
#pragma unroll
        for (int i = 0; i < 32; i++) w[i] = root1[i * 32 + c];
        b = b1[c];
    } else {
        int c = t - 224;
#pragma unroll
        for (int i = 0; i < 32; i++) w[i] = roots[i * 32 + c];
        b = bs[c];
    }
    __shared__ float xs[8 * 32];
    for (int n0 = blockIdx.x * 8; n0 < NN; n0 += gridDim.x * 8) {
        int rows = NN - n0; if (rows > 8) rows = 8;
        for (int j = t; j < rows * 32; j += 256) xs[j] = x[(size_t)n0 * 32 + j];
        __syncthreads();
        for (int r = 0; r < rows; r++) {
            float acc = b;
#pragma unroll
            for (int i = 0; i < 32; i++) acc += w[i] * xs[r * 32 + i];
            int n = n0 + r;
            if (t < 192) PA[(size_t)n * 192 + t] = __float2half(acc);
            else if (t < 224) R1[(size_t)n * 32 + (t - 192)] = acc;
            else Rs[(size_t)n * 32 + (t - 224)] = acc;
        }
        __syncthreads();
    }
}

// pass B projection: h -> PB[n][160] fp16, R2[n][32] fp32. block=192.
__global__ void projB_kernel(const float* __restrict__ h, const float* __restrict__ g2,
                             const float* __restrict__ root2, const float* __restrict__ b2,
                             __half* __restrict__ PB, float* __restrict__ R2) {
    const int t = threadIdx.x;
    float w[32];
    float b = 0.0f;
    if (t < 160) {
#pragma unroll
        for (int i = 0; i < 32; i++) w[i] = g2[i * 160 + t];
    } else {
        int c = t - 160;
#pragma unroll
        for (int i = 0; i < 32; i++) w[i] = root2[i * 32 + c];
        b = b2[c];
    }
    __shared__ float xs[8 * 32];
    for (int n0 = blockIdx.x * 8; n0 < NN; n0 += gridDim.x * 8) {
        int rows = NN - n0; if (rows > 8) rows = 8;
        for (int j = t; j < rows * 32; j += 192) xs[j] = h[(size_t)n0 * 32 + j];
        __syncthreads();
        for (int r = 0; r < rows; r++) {
            float acc = b;
#pragma unroll
            for (int i = 0; i < 32; i++) acc += w[i] * xs[r * 32 + i];
            int n = n0 + r;
            if (t < 160) PB[(size_t)n * 160 + t] = __float2half(acc);
            else R2[(size_t)n * 32 + (t - 160)] = acc;
        }
        __syncthreads();
    }
}

// CSR node-gather aggregate. One wave per node; lanes 0-31 = channels for edge i,
// lanes 32-63 = channels for edge i+1; cross-half shuffle-reduce at the end.
// Fuses mean + root-term add + BN-stats accumulation. SKIP adds the K=1 skip conv.
template <bool SKIP>
__global__ void agg_kernel(const int* __restrict__ srcs, const __half* __restrict__ wK,
                           const __half* __restrict__ wS, const int* __restrict__ rowstart,
                           const int* __restrict__ deg, const __half* __restrict__ P,
                           int pstride, const float* __restrict__ R,
                           const float* __restrict__ Rs, float* __restrict__ c,
                           float* __restrict__ cs, float* __restrict__ stats) {
    const int tid = blockIdx.x * blockDim.x + threadIdx.x;
    const int lane = threadIdx.x & 63;
    const int half = lane >> 5;
    const int ch = lane & 31;
    const int wavesTotal = (gridDim.x * blockDim.x) >> 6;
    const int wid = tid >> 6;

    float s1 = 0.f, q1 = 0.f, ss = 0.f, qs = 0.f;
    for (int n = wid; n < NN; n += wavesTotal) {
        const int start = rowstart[n];
        const int d = deg[n];
        float m1 = 0.f, mS = 0.f;
        for (int i = half; i < d; i += 2) {
            const int pos = start + i;
            const int s = srcs[pos];
            const __half* prow = P + (size_t)s * pstride;
#pragma unroll
            for (int k = 0; k < 5; k++) {
                float w = __half2float(wK[(size_t)pos * 5 + k]);
                m1 += w * __half2float(prow[k * 32 + ch]);
            }
            if (SKIP) mS += __half2float(wS[pos]) * __half2float(prow[160 + ch]);
        }
        m1 += __shfl_xor(m1, 32, 64);
        if (SKIP) mS += __shfl_xor(mS, 32, 64);
        const float invd = 1.0f / fmaxf((float)d, 1.0f);
        if (half == 0) {
            float v = m1 * invd + R[(size_t)n * 32 + ch];
            c[(size_t)n * 32 + ch] = v;
            s1 += v; q1 += v * v;
            if (SKIP) {
                float vs = mS * invd + Rs[(size_t)n * 32 + ch];
                cs[(size_t)n * 32 + ch] = vs;
                ss += vs; qs += vs * vs;
            }
        }
    }
    __shared__ float sh[128];
    const int t = threadIdx.x;
    if (t < 128) sh[t] = 0.f;
    __syncthreads();
    if (half == 0) {
        atomicAdd(&sh[ch], s1);
        atomicAdd(&sh[32 + ch], q1);
        if (SKIP) { atomicAdd(&sh[64 + ch], ss); atomicAdd(&sh[96 + ch], qs); }
    }
    __syncthreads();
    if (SKIP) { if (t < 128) atomicAdd(&stats[t], sh[t]); }
    else      { if (t < 64)  atomicAdd(&stats[t], sh[t]); }
}

// h = elu(bn(c1)); s = bn(cs). stats layout: [sum1|sq1|sumS|sqS]
__global__ void apply1_kernel(const float* __restrict__ c1, const float* __restrict__ cs,
                              const float* __restrict__ stats, const float* __restrict__ gam1,
                              const float* __restrict__ bet1, const float* __restrict__ gams,
                              const float* __restrict__ bets, float* __restrict__ h,
                              float* __restrict__ s_out) {
    int idx = blockIdx.x * blockDim.x + threadIdx.x;
    if (idx >= NN * 32) return;
    int ch = idx & 31;
    const float invN = 1.0f / (float)NN;
    float m1 = stats[ch] * invN;
    float v1 = stats[32 + ch] * invN - m1 * m1;
    float hv = gam1[ch] * (c1[idx] - m1) * rsqrtf(v1 + BN_EPS) + bet1[ch];
    h[idx] = hv > 0.f ? hv : (__expf(hv) - 1.f);
    float ms = stats[64 + ch] * invN;
    float vs = stats[96 + ch] * invN - ms * ms;
    s_out[idx] = gams[ch] * (cs[idx] - ms) * rsqrtf(vs + BN_EPS) + bets[ch];
}

// out = elu(bn(c2) + s)
__global__ void apply2_kernel(const float* __restrict__ c2, const float* __restrict__ s_in,
                              const float* __restrict__ stats, const float* __restrict__ gam2,
                              const float* __restrict__ bet2, float* __restrict__ out) {
    int idx = blockIdx.x * blockDim.x + threadIdx.x;
    if (idx >= NN * 32) return;
    int ch = idx & 31;
    const float invN = 1.0f / (float)NN;
    float m = stats[ch] * invN;
    float v = stats[32 + ch] * invN - m * m;
    float o = gam2[ch] * (c2[idx] - m) * rsqrtf(v + BN_EPS) + bet2[ch] + s_in[idx];
    out[idx] = o > 0.f ? o : (__expf(o) - 1.f);
}

extern "C" void kernel_launch(void* const* d_in, const int* in_sizes, int n_in,
                              void* d_out, int out_size, void* d_ws, size_t ws_size,
                              hipStream_t stream) {
    const float* x     = (const float*)d_in[0];
    const float* ea    = (const float*)d_in[1];
    const float* g1    = (const float*)d_in[2];
    const float* mu1   = (const float*)d_in[3];
    const float* sig1  = (const float*)d_in[4];
    const float* root1 = (const float*)d_in[5];
    const float* b1    = (const float*)d_in[6];
    const float* gam1  = (const float*)d_in[7];
    const float* bet1  = (const float*)d_in[8];
    const float* g2    = (const float*)d_in[9];
    const float* mu2   = (const float*)d_in[10];
    const float* sig2  = (const float*)d_in[11];
    const float* root2 = (const float*)d_in[12];
    const float* b2    = (const float*)d_in[13];
    const float* gam2  = (const float*)d_in[14];
    const float* bet2  = (const float*)d_in[15];
    const float* gs    = (const float*)d_in[16];
    const float* mus   = (const float*)d_in[17];
    const float* sigs  = (const float*)d_in[18];
    const float* roots = (const float*)d_in[19];
    const float* bs    = (const float*)d_in[20];
    const float* gams  = (const float*)d_in[21];
    const float* bets  = (const float*)d_in[22];
    const int*   ei    = (const int*)d_in[23];
    float* out = (float*)d_out;

    // ---- workspace layout (bytes) ----
    char* w = (char*)d_ws;
    __half* PA   = (__half*)w;              w += (size_t)NN * 192 * 2;  // 19.2 MB (reused as PB)
    float*  R1   = (float*)w;               w += (size_t)NN * 32 * 4;   // 6.4 MB (reused as R2)
    float*  Rs   = (float*)w;               w += (size_t)NN * 32 * 4;
    float*  c1   = (float*)w;               w += (size_t)NN * 32 * 4;   // reused as c2
    float*  cs   = (float*)w;               w += (size_t)NN * 32 * 4;
    float*  h    = (float*)w;               w += (size_t)NN * 32 * 4;
    float*  sbuf = (float*)w;               w += (size_t)NN * 32 * 4;
    int*    srcs = (int*)w;                 w += (size_t)NE * 4;        // 3.2 MB
    __half* wA   = (__half*)w;              w += (size_t)NE * 5 * 2;    // 8 MB
    __half* wB   = (__half*)w;              w += (size_t)NE * 5 * 2;    // 8 MB
    __half* wS   = (__half*)w;              w += (size_t)NE * 2;        // 1.6 MB
    int*    deg  = (int*)w;                 w += (size_t)NN * 4;
    int*    rowstart = (int*)w;             w += (size_t)NN * 4;
    int*    cursor   = (int*)w;             w += (size_t)NN * 4;
    float*  stats = (float*)w;              w += 256 * 4;               // F: [0..127]=A, [128..191]=B
    float*  inv   = (float*)w;              w += 64 * 4;

    const int edgeBlocks  = (NE + 255) / 256;
    const int applyBlocks = (NN * 32 + 255) / 256;

    hipMemsetAsync(deg, 0, NN * sizeof(int), stream);
    hipMemsetAsync(stats, 0, 256 * sizeof(float), stream);
    precompute_inv<<<1, 64, 0, stream>>>(sig1, sig2, sigs, inv);

    // ---- CSR build (once, shared by all 3 convs) ----
    hist_kernel<<<edgeBlocks, 256, 0, stream>>>(ei, deg);
    scan_kernel<<<1, 1024, 0, stream>>>(deg, rowstart, cursor);
    reorder_kernel<<<edgeBlocks, 256, 0, stream>>>(ei, ea, mu1, mu2, mus, inv, cursor,
                                                   srcs, wA, wB, wS);

    // ---- pass A: conv1 + skip fused ----
    projA_kernel<<<512, 256, 0, stream>>>(x, g1, gs, root1, b1, roots, bs, PA, R1, Rs);
    agg_kernel<true><<<1600, 256, 0, stream>>>(srcs, wA, wS, rowstart, deg, PA, 192,
                                               R1, Rs, c1, cs, stats);
    apply1_kernel<<<applyBlocks, 256, 0, stream>>>(c1, cs, stats, gam1, bet1, gams, bets,
                                                   h, sbuf);

    // ---- pass B: conv2 on h, then out = elu(bn(c2) + s) ----
    projB_kernel<<<512, 192, 0, stream>>>(h, g2, root2, b2, PA, R1);  // PA/R1 reused
    agg_kernel<false><<<1600, 256, 0, stream>>>(srcs, wB, nullptr, rowstart, deg, PA, 160,
                                                R1, nullptr, c1, nullptr, stats + 128);
    apply2_kernel<<<applyBlocks, 256, 0, stream>>>(c1, sbuf, stats + 128, gam2, bet2, out);
}

// Round 3
// 430.871 us; speedup vs baseline: 1.4090x; 1.3430x over previous
//
#include <hip/hip_runtime.h>
#include <hip/hip_fp16.h>
#include <math.h>

#define NN 50000
#define NE 800000
#define GEPS 1e-15f
#define BN_EPS 1e-5f
#define NB 196  // (NN+255)/256

struct __align__(16) EdgeRec {
    int src;
    __half w[11];   // [0..4]=conv1, [5..9]=conv2, [10]=skip
    __half pad;
};

// inv[k*3+d] = -0.5/(eps + sigma^2): [0..14]=conv1, [15..29]=conv2, [30..32]=skip
__global__ void precompute_inv(const float* __restrict__ sig1, const float* __restrict__ sig2,
                               const float* __restrict__ sigs, float* __restrict__ inv) {
    int t = threadIdx.x;
    if (t < 15)      { float s = sig1[t];      inv[t] = -0.5f / (GEPS + s * s); }
    else if (t < 30) { float s = sig2[t - 15]; inv[t] = -0.5f / (GEPS + s * s); }
    else if (t < 33) { float s = sigs[t - 30]; inv[t] = -0.5f / (GEPS + s * s); }
}

__global__ void hist_kernel(const int* __restrict__ ei, int* __restrict__ deg) {
    int e = blockIdx.x * blockDim.x + threadIdx.x;
    if (e < NE) atomicAdd(&deg[ei[NE + e]], 1);
}

// ---- two-level scan ----
__global__ void block_reduce_kernel(const int* __restrict__ deg, int* __restrict__ bsum) {
    __shared__ int sh[256];
    int t = threadIdx.x;
    int i = blockIdx.x * 256 + t;
    sh[t] = (i < NN) ? deg[i] : 0;
    __syncthreads();
    for (int off = 128; off > 0; off >>= 1) {
        if (t < off) sh[t] += sh[t + off];
        __syncthreads();
    }
    if (t == 0) bsum[blockIdx.x] = sh[0];
}

__global__ void scan_partials_kernel(int* __restrict__ bsum) {
    __shared__ int sh[256];
    int t = threadIdx.x;
    int v = (t < NB) ? bsum[t] : 0;
    sh[t] = v;
    __syncthreads();
    for (int off = 1; off < 256; off <<= 1) {
        int u = (t >= off) ? sh[t - off] : 0;
        __syncthreads();
        sh[t] += u;
        __syncthreads();
    }
    if (t < NB) bsum[t] = sh[t] - v;  // exclusive
}

__global__ void block_scan_kernel(const int* __restrict__ deg, const int* __restrict__ bsum,
                                  int* __restrict__ rowstart, int* __restrict__ cursor) {
    __shared__ int sh[256];
    int t = threadIdx.x;
    int i = blockIdx.x * 256 + t;
    int v = (i < NN) ? deg[i] : 0;
    sh[t] = v;
    __syncthreads();
    for (int off = 1; off < 256; off <<= 1) {
        int u = (t >= off) ? sh[t - off] : 0;
        __syncthreads();
        sh[t] += u;
        __syncthreads();
    }
    int excl = sh[t] - v + bsum[blockIdx.x];
    if (i < NN) { rowstart[i] = excl; cursor[i] = excl; }
}

// scatter edges into CSR order as packed 32B records (src + 11 fp16 gaussian weights)
__global__ void reorder_kernel(const int* __restrict__ ei, const float* __restrict__ ea,
                               const float* __restrict__ mu1, const float* __restrict__ mu2,
                               const float* __restrict__ mus, const float* __restrict__ inv,
                               int* __restrict__ cursor, int4* __restrict__ recs) {
    int e = blockIdx.x * blockDim.x + threadIdx.x;
    if (e >= NE) return;
    int src = ei[e];
    int dst = ei[NE + e];
    float a0 = ea[e * 3 + 0], a1 = ea[e * 3 + 1], a2 = ea[e * 3 + 2];

    union { EdgeRec r; int4 q[2]; } u;
    u.r.src = src;
#pragma unroll
    for (int k = 0; k < 5; k++) {
        float d0 = a0 - mu1[k * 3 + 0], d1 = a1 - mu1[k * 3 + 1], d2 = a2 - mu1[k * 3 + 2];
        float ex = inv[k * 3] * d0 * d0 + inv[k * 3 + 1] * d1 * d1 + inv[k * 3 + 2] * d2 * d2;
        u.r.w[k] = __float2half(__expf(ex));
    }
#pragma unroll
    for (int k = 0; k < 5; k++) {
        float d0 = a0 - mu2[k * 3 + 0], d1 = a1 - mu2[k * 3 + 1], d2 = a2 - mu2[k * 3 + 2];
        float ex = inv[15 + k * 3] * d0 * d0 + inv[15 + k * 3 + 1] * d1 * d1 + inv[15 + k * 3 + 2] * d2 * d2;
        u.r.w[5 + k] = __float2half(__expf(ex));
    }
    {
        float d0 = a0 - mus[0], d1 = a1 - mus[1], d2 = a2 - mus[2];
        float ex = inv[30] * d0 * d0 + inv[31] * d1 * d1 + inv[32] * d2 * d2;
        u.r.w[10] = __float2half(__expf(ex));
    }
    u.r.pad = __float2half(0.f);

    int pos = atomicAdd(&cursor[dst], 1);
    recs[(size_t)pos * 2]     = u.q[0];
    recs[(size_t)pos * 2 + 1] = u.q[1];
}

// pass A projection: x -> PA[n][192] fp16 (0..159: g1-proj, 160..191: gs-proj),
//                    R1[n][32] fp32 (x@root1+b1), Rs[n][32] fp32 (x@roots+bs). block=256.
__global__ void projA_kernel(const float* __restrict__ x, const float* __restrict__ g1,
                             const float* __restrict__ gs, const float* __restrict__ root1,
                             const float* __restrict__ b1, const float* __restrict__ roots,
                             const float* __restrict__ bs, __half* __restrict__ PA,
                             float* __restrict__ R1, float* __restrict__ Rs) {
    const int t = threadIdx.x;
    float w[32];
    float b = 0.0f;
    if (t < 160) {
#pragma unroll
        for (int i = 0; i < 32; i++) w[i] = g1[i * 160 + t];
    } else if (t < 192) {
        int c = t - 160;
#pragma unroll
        for (int i = 0; i < 32; i++) w[i] = gs[i * 32 + c];
    } else if (t < 224) {
        int c = t - 192;
#pragma unroll
        for (int i = 0; i < 32; i++) w[i] = root1[i * 32 + c];
        b = b1[c];
    } else {
        int c = t - 224;
#pragma unroll
        for (int i = 0; i < 32; i++) w[i] = roots[i * 32 + c];
        b = bs[c];
    }
    __shared__ float xs[8 * 32];
    for (int n0 = blockIdx.x * 8; n0 < NN; n0 += gridDim.x * 8) {
        int rows = NN - n0; if (rows > 8) rows = 8;
        for (int j = t; j < rows * 32; j += 256) xs[j] = x[(size_t)n0 * 32 + j];
        __syncthreads();
        for (int r = 0; r < rows; r++) {
            float acc = b;
#pragma unroll
            for (int i = 0; i < 32; i++) acc += w[i] * xs[r * 32 + i];
            int n = n0 + r;
            if (t < 192) PA[(size_t)n * 192 + t] = __float2half(acc);
            else if (t < 224) R1[(size_t)n * 32 + (t - 192)] = acc;
            else Rs[(size_t)n * 32 + (t - 224)] = acc;
        }
        __syncthreads();
    }
}

// pass B projection: h -> PB[n][160] fp16, R2[n][32] fp32. block=192.
__global__ void projB_kernel(const float* __restrict__ h, const float* __restrict__ g2,
                             const float* __restrict__ root2, const float* __restrict__ b2,
                             __half* __restrict__ PB, float* __restrict__ R2) {
    const int t = threadIdx.x;
    float w[32];
    float b = 0.0f;
    if (t < 160) {
#pragma unroll
        for (int i = 0; i < 32; i++) w[i] = g2[i * 160 + t];
    } else {
        int c = t - 160;
#pragma unroll
        for (int i = 0; i < 32; i++) w[i] = root2[i * 32 + c];
        b = b2[c];
    }
    __shared__ float xs[8 * 32];
    for (int n0 = blockIdx.x * 8; n0 < NN; n0 += gridDim.x * 8) {
        int rows = NN - n0; if (rows > 8) rows = 8;
        for (int j = t; j < rows * 32; j += 192) xs[j] = h[(size_t)n0 * 32 + j];
        __syncthreads();
        for (int r = 0; r < rows; r++) {
            float acc = b;
#pragma unroll
            for (int i = 0; i < 32; i++) acc += w[i] * xs[r * 32 + i];
            int n = n0 + r;
            if (t < 160) PB[(size_t)n * 160 + t] = __float2half(acc);
            else R2[(size_t)n * 32 + (t - 160)] = acc;
        }
        __syncthreads();
    }
}

// CSR node-gather aggregate. One wave per node. 4 groups of 16 lanes; group g handles
// edges i%4==g; each lane owns a channel PAIR (half2 loads, float2 accum).
// Cross-group reduce via shfl_xor(16/32). Fuses mean + root add + BN stats.
// WOFF: weight offset in record (0=conv1, 5=conv2). SKIP adds the K=1 skip conv.
template <bool SKIP, int WOFF>
__global__ void agg_kernel(const EdgeRec* __restrict__ recs, const int* __restrict__ rowstart,
                           const int* __restrict__ deg, const __half2* __restrict__ P,
                           int strideH2, const float* __restrict__ R,
                           const float* __restrict__ Rs, float* __restrict__ c,
                           float* __restrict__ cs, float* __restrict__ stats) {
    const int tid = blockIdx.x * blockDim.x + threadIdx.x;
    const int lane = threadIdx.x & 63;
    const int grp = lane >> 4;        // 0..3: edge subgroup
    const int ch2 = lane & 15;        // channel pair index
    const int wavesTotal = (gridDim.x * blockDim.x) >> 6;
    const int wid = tid >> 6;

    float s1x = 0.f, s1y = 0.f, q1x = 0.f, q1y = 0.f;
    float ssx = 0.f, ssy = 0.f, qsx = 0.f, qsy = 0.f;

    for (int n = wid; n < NN; n += wavesTotal) {
        const int start = rowstart[n];
        const int d = deg[n];
        float m1x = 0.f, m1y = 0.f, mSx = 0.f, mSy = 0.f;
        for (int i = grp; i < d; i += 4) {
            const EdgeRec* rec = recs + (size_t)(start + i);
            const int s = rec->src;
            const __half2* prow = P + (size_t)s * strideH2 + ch2;
#pragma unroll
            for (int k = 0; k < 5; k++) {
                float wk = __half2float(rec->w[WOFF + k]);
                float2 p = __half22float2(prow[k * 16]);
                m1x += wk * p.x;
                m1y += wk * p.y;
            }
            if (SKIP) {
                float ws = __half2float(rec->w[10]);
                float2 p = __half22float2(prow[80]);
                mSx += ws * p.x;
                mSy += ws * p.y;
            }
        }
        m1x += __shfl_xor(m1x, 16, 64); m1x += __shfl_xor(m1x, 32, 64);
        m1y += __shfl_xor(m1y, 16, 64); m1y += __shfl_xor(m1y, 32, 64);
        if (SKIP) {
            mSx += __shfl_xor(mSx, 16, 64); mSx += __shfl_xor(mSx, 32, 64);
            mSy += __shfl_xor(mSy, 16, 64); mSy += __shfl_xor(mSy, 32, 64);
        }
        const float invd = 1.0f / fmaxf((float)d, 1.0f);
        if (grp == 0) {
            const float2* rr = (const float2*)(R + (size_t)n * 32);
            float2 rv = rr[ch2];
            float vx = m1x * invd + rv.x;
            float vy = m1y * invd + rv.y;
            ((float2*)(c + (size_t)n * 32))[ch2] = make_float2(vx, vy);
            s1x += vx; s1y += vy; q1x += vx * vx; q1y += vy * vy;
            if (SKIP) {
                float2 rs = ((const float2*)(Rs + (size_t)n * 32))[ch2];
                float wx = mSx * invd + rs.x;
                float wy = mSy * invd + rs.y;
                ((float2*)(cs + (size_t)n * 32))[ch2] = make_float2(wx, wy);
                ssx += wx; ssy += wy; qsx += wx * wx; qsy += wy * wy;
            }
        }
    }
    __shared__ float sh[128];
    const int t = threadIdx.x;
    if (t < 128) sh[t] = 0.f;
    __syncthreads();
    if (grp == 0) {
        atomicAdd(&sh[2 * ch2], s1x);       atomicAdd(&sh[2 * ch2 + 1], s1y);
        atomicAdd(&sh[32 + 2 * ch2], q1x);  atomicAdd(&sh[32 + 2 * ch2 + 1], q1y);
        if (SKIP) {
            atomicAdd(&sh[64 + 2 * ch2], ssx);  atomicAdd(&sh[64 + 2 * ch2 + 1], ssy);
            atomicAdd(&sh[96 + 2 * ch2], qsx);  atomicAdd(&sh[96 + 2 * ch2 + 1], qsy);
        }
    }
    __syncthreads();
    if (SKIP) { if (t < 128) atomicAdd(&stats[t], sh[t]); }
    else      { if (t < 64)  atomicAdd(&stats[t], sh[t]); }
}

// h = elu(bn(c1)); s = bn(cs). stats layout: [sum1|sq1|sumS|sqS]
__global__ void apply1_kernel(const float* __restrict__ c1, const float* __restrict__ cs,
                              const float* __restrict__ stats, const float* __restrict__ gam1,
                              const float* __restrict__ bet1, const float* __restrict__ gams,
                              const float* __restrict__ bets, float* __restrict__ h,
                              float* __restrict__ s_out) {
    int idx = blockIdx.x * blockDim.x + threadIdx.x;
    if (idx >= NN * 32) return;
    int ch = idx & 31;
    const float invN = 1.0f / (float)NN;
    float m1 = stats[ch] * invN;
    float v1 = stats[32 + ch] * invN - m1 * m1;
    float hv = gam1[ch] * (c1[idx] - m1) * rsqrtf(v1 + BN_EPS) + bet1[ch];
    h[idx] = hv > 0.f ? hv : (__expf(hv) - 1.f);
    float ms = stats[64 + ch] * invN;
    float vs = stats[96 + ch] * invN - ms * ms;
    s_out[idx] = gams[ch] * (cs[idx] - ms) * rsqrtf(vs + BN_EPS) + bets[ch];
}

// out = elu(bn(c2) + s)
__global__ void apply2_kernel(const float* __restrict__ c2, const float* __restrict__ s_in,
                              const float* __restrict__ stats, const float* __restrict__ gam2,
                              const float* __restrict__ bet2, float* __restrict__ out) {
    int idx = blockIdx.x * blockDim.x + threadIdx.x;
    if (idx >= NN * 32) return;
    int ch = idx & 31;
    const float invN = 1.0f / (float)NN;
    float m = stats[ch] * invN;
    float v = stats[32 + ch] * invN - m * m;
    float o = gam2[ch] * (c2[idx] - m) * rsqrtf(v + BN_EPS) + bet2[ch] + s_in[idx];
    out[idx] = o > 0.f ? o : (__expf(o) - 1.f);
}

extern "C" void kernel_launch(void* const* d_in, const int* in_sizes, int n_in,
                              void* d_out, int out_size, void* d_ws, size_t ws_size,
                              hipStream_t stream) {
    const float* x     = (const float*)d_in[0];
    const float* ea    = (const float*)d_in[1];
    const float* g1    = (const float*)d_in[2];
    const float* mu1   = (const float*)d_in[3];
    const float* sig1  = (const float*)d_in[4];
    const float* root1 = (const float*)d_in[5];
    const float* b1    = (const float*)d_in[6];
    const float* gam1  = (const float*)d_in[7];
    const float* bet1  = (const float*)d_in[8];
    const float* g2    = (const float*)d_in[9];
    const float* mu2   = (const float*)d_in[10];
    const float* sig2  = (const float*)d_in[11];
    const float* root2 = (const float*)d_in[12];
    const float* b2    = (const float*)d_in[13];
    const float* gam2  = (const float*)d_in[14];
    const float* bet2  = (const float*)d_in[15];
    const float* gs    = (const float*)d_in[16];
    const float* mus   = (const float*)d_in[17];
    const float* sigs  = (const float*)d_in[18];
    const float* roots = (const float*)d_in[19];
    const float* bs    = (const float*)d_in[20];
    const float* gams  = (const float*)d_in[21];
    const float* bets  = (const float*)d_in[22];
    const int*   ei    = (const int*)d_in[23];
    float* out = (float*)d_out;

    // ---- workspace layout ----
    char* w = (char*)d_ws;
    __half* PA   = (__half*)w;      w += (size_t)NN * 192 * 2;  // 19.2 MB (reused as PB)
    float*  R1   = (float*)w;       w += (size_t)NN * 32 * 4;   // (reused as R2)
    float*  Rs   = (float*)w;       w += (size_t)NN * 32 * 4;
    float*  c1   = (float*)w;       w += (size_t)NN * 32 * 4;   // (reused as c2)
    float*  cs   = (float*)w;       w += (size_t)NN * 32 * 4;
    float*  h    = (float*)w;       w += (size_t)NN * 32 * 4;
    float*  sbuf = (float*)w;       w += (size_t)NN * 32 * 4;
    EdgeRec* recs = (EdgeRec*)w;    w += (size_t)NE * 32;       // 25.6 MB
    int*    deg  = (int*)w;         w += (size_t)NN * 4;
    int*    rowstart = (int*)w;     w += (size_t)NN * 4;
    int*    cursor   = (int*)w;     w += (size_t)NN * 4;
    int*    bsum = (int*)w;         w += 256 * 4;
    float*  stats = (float*)w;      w += 256 * 4;               // [0..127]=pass A, [128..191]=pass B
    float*  inv   = (float*)w;      w += 64 * 4;

    const int edgeBlocks  = (NE + 255) / 256;
    const int applyBlocks = (NN * 32 + 255) / 256;

    hipMemsetAsync(deg, 0, NN * sizeof(int), stream);
    hipMemsetAsync(stats, 0, 256 * sizeof(float), stream);
    precompute_inv<<<1, 64, 0, stream>>>(sig1, sig2, sigs, inv);

    // ---- CSR build (once, shared by all 3 convs) ----
    hist_kernel<<<edgeBlocks, 256, 0, stream>>>(ei, deg);
    block_reduce_kernel<<<NB, 256, 0, stream>>>(deg, bsum);
    scan_partials_kernel<<<1, 256, 0, stream>>>(bsum);
    block_scan_kernel<<<NB, 256, 0, stream>>>(deg, bsum, rowstart, cursor);
    reorder_kernel<<<edgeBlocks, 256, 0, stream>>>(ei, ea, mu1, mu2, mus, inv, cursor,
                                                   (int4*)recs);

    // ---- pass A: conv1 + skip fused ----
    projA_kernel<<<512, 256, 0, stream>>>(x, g1, gs, root1, b1, roots, bs, PA, R1, Rs);
    agg_kernel<true, 0><<<1600, 256, 0, stream>>>(recs, rowstart, deg, (const __half2*)PA, 96,
                                                  R1, Rs, c1, cs, stats);
    apply1_kernel<<<applyBlocks, 256, 0, stream>>>(c1, cs, stats, gam1, bet1, gams, bets,
                                                   h, sbuf);

    // ---- pass B: conv2 on h, then out = elu(bn(c2) + s) ----
    projB_kernel<<<512, 192, 0, stream>>>(h, g2, root2, b2, PA, R1);  // PA/R1 reused
    agg_kernel<false, 5><<<1600, 256, 0, stream>>>(recs, rowstart, deg, (const __half2*)PA, 80,
                                                   R1, nullptr, c1, nullptr, stats + 128);
    apply2_kernel<<<applyBlocks, 256, 0, stream>>>(c1, sbuf, stats + 128, gam2, bet2, out);
}